// Round 1
// baseline (365.350 us; speedup 1.0000x reference)
//
#include <hip/hip_runtime.h>

#define LOG2E 1.4426950408889634f

// ---------------- ws layout (bytes) ----------------
// 0        : wk_eff f32 [8][512]          (16384 B)
// 16384    : kbias  f32 [8]               (32 B)
// 16416    : q2     f32 [512]             (2048 B)
// 18464    : seg    i32 [4097]            (16388 B, padded)
// 34880    : S_ws   bf16 [8][4096][512]   (33554432 B)
// 33589312 : attn   bf16 [4096][512]      (4194304 B)
#define WK_OFF   ((size_t)0)
#define KB_OFF   ((size_t)16384)
#define Q2_OFF   ((size_t)16416)
#define SEG_OFF  ((size_t)18464)
#define S_OFF    ((size_t)34880)
#define ATTN_OFF ((size_t)33589312)
#define WS_NEEDED (ATTN_OFF + (size_t)4096*512*2)

__device__ __forceinline__ float readlane_f(float v, int l) {
  return __int_as_float(__builtin_amdgcn_readlane(__float_as_int(v), l));
}

__device__ __forceinline__ unsigned short f2bf(float x) {
  unsigned u = __float_as_uint(x);
  unsigned r = (u + 0x7fffu + ((u >> 16) & 1u)) >> 16;
  return (unsigned short)r;
}

// ---------------- K1a: q2[d] = (qry . Wq[d,:] + bq[d]) * (1/8) * log2(e) ----------------
__global__ __launch_bounds__(256) void k_q2(const float* __restrict__ qry,
                                            const float* __restrict__ Wq,
                                            const float* __restrict__ bq,
                                            float* __restrict__ q2) {
  int d = blockIdx.x * 256 + threadIdx.x;   // grid 2x256 = 512
  const float4* q4 = (const float4*)qry;
  const float4* w4 = (const float4*)(Wq + (size_t)d * 512);
  float acc = 0.f;
  #pragma unroll 4
  for (int j = 0; j < 128; ++j) {
    float4 a = q4[j], b = w4[j];
    acc += a.x * b.x + a.y * b.y + a.z * b.z + a.w * b.w;
  }
  q2[d] = (acc + bq[d]) * (0.125f * LOG2E);
}

// ---------------- K1b: wk_eff[h][e] = sum_d q2[h*64+d]*Wk[h*64+d][e]; kbias ----------------
__global__ __launch_bounds__(256) void k_wk(const float* __restrict__ Wk,
                                            const float* __restrict__ bk,
                                            const float* __restrict__ q2,
                                            float* __restrict__ wk,
                                            float* __restrict__ kb) {
  if (blockIdx.x == 16) {
    int h = threadIdx.x;
    if (h < 8) {
      float acc = 0.f;
      for (int dd = 0; dd < 64; ++dd) acc += q2[h * 64 + dd] * bk[h * 64 + dd];
      kb[h] = acc;
    }
    return;
  }
  int id = blockIdx.x * 256 + threadIdx.x;  // 0..4095
  int h = id >> 9, e = id & 511;
  float acc = 0.f;
  #pragma unroll 4
  for (int dd = 0; dd < 64; ++dd)
    acc += q2[h * 64 + dd] * Wk[(size_t)(h * 64 + dd) * 512 + e];
  wk[id] = acc;
}

// ---------------- K1c: segment starts via lower_bound; auto-detect int32/int64 batch ----------------
__global__ __launch_bounds__(256) void k_seg(const void* __restrict__ batch, int n,
                                             int* __restrict__ seg) {
  int b = blockIdx.x * 256 + threadIdx.x;
  if (b > 4096) return;
  const int* b32 = (const int*)batch;
  const long long* b64 = (const long long*)batch;
  // if int64: dword[n-1] is a high word == 0; if int32: it's the (sorted) max segment id > 0
  bool is64 = (b32[n - 1] == 0);
  int lo = 0, hi = n;
  while (lo < hi) {
    int mid = (lo + hi) >> 1;
    long long v = is64 ? b64[mid] : (long long)b32[mid];
    if (v < (long long)b) lo = mid + 1; else hi = mid;
  }
  seg[b] = lo;
}

// ---------------- K2: per-graph fused scores + softmax + weighted-emb pooling ----------------
__global__ __launch_bounds__(256, 2) void k_main(const float* __restrict__ emb,
                                                 const int* __restrict__ seg,
                                                 const float* __restrict__ wk,
                                                 const float* __restrict__ kb,
                                                 unsigned short* __restrict__ S_ws) {
  __shared__ float sm[8232];
  const int tid = threadIdx.x;
  const int lane = tid & 63, wave = tid >> 6;
  const int b = blockIdx.x;
  const int s = seg[b], e2 = seg[b + 1];

  // per-lane wk_eff fragments: lane owns e in {4l..4l+3} U {256+4l..256+4l+3}
  float4 wka[8], wkb[8];
  #pragma unroll
  for (int h = 0; h < 8; ++h) {
    wka[h] = *(const float4*)(wk + h * 512 + 4 * lane);
    wkb[h] = *(const float4*)(wk + h * 512 + 256 + 4 * lane);
  }
  const float kbl = kb[lane & 7];

  float4 Sa[8], Sb[8];
  #pragma unroll
  for (int h = 0; h < 8; ++h) {
    Sa[h] = make_float4(0.f, 0.f, 0.f, 0.f);
    Sb[h] = make_float4(0.f, 0.f, 0.f, 0.f);
  }
  float dn = 0.f;

  const float4* emb4 = (const float4*)emb;
  const int pw = wave * 832 + lane * 13;                    // write base (row=lane)
  const int pr = wave * 832 + (lane & 56) * 13 + (lane & 7); // read base (col=lane&7)

  int i = s + wave;
  if (i < e2) {
    size_t off = (size_t)i * 128 + lane;
    float4 a0 = emb4[off], a1 = emb4[off + 64];
    while (true) {
      int nx = i + 4;
      bool more = nx < e2;
      float4 b0, b1;
      if (more) {
        size_t o2 = (size_t)nx * 128 + lane;
        b0 = emb4[o2];
        b1 = emb4[o2 + 64];
      }
      // per-lane score partials for all 8 heads
      float p[8];
      #pragma unroll
      for (int h = 0; h < 8; ++h) {
        float4 wa = wka[h], wb = wkb[h];
        p[h] = a0.x * wa.x + a0.y * wa.y + a0.z * wa.z + a0.w * wa.w +
               a1.x * wb.x + a1.y * wb.y + a1.z * wb.z + a1.w * wb.w;
      }
      // LDS transpose (row pad 13 floats -> conflict-free-ish), 8-lane-group partial sums
      #pragma unroll
      for (int h = 0; h < 8; ++h) sm[pw + h] = p[h];
      float hs = 0.f;
      #pragma unroll
      for (int j = 0; j < 8; ++j) hs += sm[pr + j * 13];
      hs += __shfl_xor(hs, 8);
      hs += __shfl_xor(hs, 16);
      hs += __shfl_xor(hs, 32);
      // every lane now holds the full score (log2-scaled) for head (lane&7)
      float w_own = exp2f(hs + kbl);
      dn += w_own;
      #pragma unroll
      for (int h = 0; h < 8; ++h) {
        float wh = readlane_f(w_own, h);
        Sa[h].x += wh * a0.x; Sa[h].y += wh * a0.y; Sa[h].z += wh * a0.z; Sa[h].w += wh * a0.w;
        Sb[h].x += wh * a1.x; Sb[h].y += wh * a1.y; Sb[h].z += wh * a1.z; Sb[h].w += wh * a1.w;
      }
      if (!more) break;
      i = nx; a0 = b0; a1 = b1;
    }
  }
  __syncthreads();

  // denominators (per wave, lanes 0..7 hold heads 0..7)
  if (lane < 8) sm[8192 + wave * 8 + lane] = dn;
  __syncthreads();
  if (tid < 8) {
    float d = sm[8192 + tid] + sm[8200 + tid] + sm[8208 + tid] + sm[8216 + tid];
    sm[8224 + tid] = (d > 0.f) ? 1.f / d : 0.f;
  }
  __syncthreads();

  // combine S across waves, half A (e < 256) then half B, write S' = S/denom as bf16
  #pragma unroll
  for (int h = 0; h < 8; ++h)
    *(float4*)&sm[wave * 2048 + h * 256 + 4 * lane] = Sa[h];
  __syncthreads();
  #pragma unroll
  for (int h = 0; h < 8; ++h) {
    float v = (sm[h * 256 + tid] + sm[2048 + h * 256 + tid] +
               sm[4096 + h * 256 + tid] + sm[6144 + h * 256 + tid]) * sm[8224 + h];
    S_ws[((size_t)h * 4096 + b) * 512 + tid] = f2bf(v);
  }
  __syncthreads();
  #pragma unroll
  for (int h = 0; h < 8; ++h)
    *(float4*)&sm[wave * 2048 + h * 256 + 4 * lane] = Sb[h];
  __syncthreads();
  #pragma unroll
  for (int h = 0; h < 8; ++h) {
    float v = (sm[h * 256 + tid] + sm[2048 + h * 256 + tid] +
               sm[4096 + h * 256 + tid] + sm[6144 + h * 256 + tid]) * sm[8224 + h];
    S_ws[((size_t)h * 4096 + b) * 512 + 256 + tid] = f2bf(v);
  }
}

// ---------------- K3/K4: C[rt*64+.., cb*64+..] = A(bf16) . W[cb*64+r,:]^T + bias ----------------
template <bool C_BF16>
__global__ __launch_bounds__(256) void k_gemm(const unsigned short* __restrict__ A,
                                              size_t a_cb_stride,
                                              const float* __restrict__ W,
                                              const float* __restrict__ bias,
                                              void* __restrict__ Cv) {
  __shared__ float At[32][72];
  __shared__ float Wt[32][72];
  const int t = threadIdx.x;
  const int rt = blockIdx.x, cb = blockIdx.y;
  const int tm = t >> 4, tn = t & 15;
  const int r = t >> 2, c0 = (t & 3) * 8;
  const unsigned short* Ab = A + (size_t)cb * a_cb_stride + (size_t)(rt * 64 + r) * 512 + c0;
  const float* Wb = W + (size_t)(cb * 64 + r) * 512 + c0;
  float acc[4][4] = {};

  for (int kc = 0; kc < 512; kc += 32) {
    uint4 ar = *(const uint4*)(Ab + kc);
    float4 w0 = *(const float4*)(Wb + kc);
    float4 w1 = *(const float4*)(Wb + kc + 4);
    __syncthreads();
    At[c0 + 0][r] = __uint_as_float(ar.x << 16);
    At[c0 + 1][r] = __uint_as_float(ar.x & 0xffff0000u);
    At[c0 + 2][r] = __uint_as_float(ar.y << 16);
    At[c0 + 3][r] = __uint_as_float(ar.y & 0xffff0000u);
    At[c0 + 4][r] = __uint_as_float(ar.z << 16);
    At[c0 + 5][r] = __uint_as_float(ar.z & 0xffff0000u);
    At[c0 + 6][r] = __uint_as_float(ar.w << 16);
    At[c0 + 7][r] = __uint_as_float(ar.w & 0xffff0000u);
    Wt[c0 + 0][r] = w0.x; Wt[c0 + 1][r] = w0.y; Wt[c0 + 2][r] = w0.z; Wt[c0 + 3][r] = w0.w;
    Wt[c0 + 4][r] = w1.x; Wt[c0 + 5][r] = w1.y; Wt[c0 + 6][r] = w1.z; Wt[c0 + 7][r] = w1.w;
    __syncthreads();
    #pragma unroll
    for (int kk = 0; kk < 32; ++kk) {
      const float4 av = *(const float4*)&At[kk][tm * 4];
      const float4 wv = *(const float4*)&Wt[kk][tn * 4];
      acc[0][0] += av.x * wv.x; acc[0][1] += av.x * wv.y; acc[0][2] += av.x * wv.z; acc[0][3] += av.x * wv.w;
      acc[1][0] += av.y * wv.x; acc[1][1] += av.y * wv.y; acc[1][2] += av.y * wv.z; acc[1][3] += av.y * wv.w;
      acc[2][0] += av.z * wv.x; acc[2][1] += av.z * wv.y; acc[2][2] += av.z * wv.z; acc[2][3] += av.z * wv.w;
      acc[3][0] += av.w * wv.x; acc[3][1] += av.w * wv.y; acc[3][2] += av.w * wv.z; acc[3][3] += av.w * wv.w;
    }
  }

  const float4 bb = *(const float4*)(bias + cb * 64 + tn * 4);
  #pragma unroll
  for (int i2 = 0; i2 < 4; ++i2) {
    float x0 = acc[i2][0] + bb.x;
    float x1 = acc[i2][1] + bb.y;
    float x2 = acc[i2][2] + bb.z;
    float x3 = acc[i2][3] + bb.w;
    size_t row = (size_t)(rt * 64 + tm * 4 + i2);
    size_t col = (size_t)(cb * 64 + tn * 4);
    if (C_BF16) {
      unsigned int lo = (unsigned int)f2bf(x0) | ((unsigned int)f2bf(x1) << 16);
      unsigned int hi = (unsigned int)f2bf(x2) | ((unsigned int)f2bf(x3) << 16);
      *(uint2*)((unsigned short*)Cv + row * 512 + col) = make_uint2(lo, hi);
    } else {
      *(float4*)((float*)Cv + row * 512 + col) = make_float4(x0, x1, x2, x3);
    }
  }
}

// ---------------- launcher ----------------
extern "C" void kernel_launch(void* const* d_in, const int* in_sizes, int n_in,
                              void* d_out, int out_size, void* d_ws, size_t ws_size,
                              hipStream_t stream) {
  const float* emb  = (const float*)d_in[0];
  const void*  batch = d_in[1];
  const float* qry  = (const float*)d_in[2];
  const float* Wq   = (const float*)d_in[3];
  const float* bq   = (const float*)d_in[4];
  const float* Wk   = (const float*)d_in[5];
  const float* bk   = (const float*)d_in[6];
  const float* Wv   = (const float*)d_in[7];
  const float* bv   = (const float*)d_in[8];
  const float* Wo   = (const float*)d_in[9];
  const float* bo   = (const float*)d_in[10];
  const int N = in_sizes[1];

  if (ws_size < WS_NEEDED) return;  // scratch too small: leave output poisoned (clear failure)

  char* ws = (char*)d_ws;
  float* q2     = (float*)(ws + Q2_OFF);
  float* wk_eff = (float*)(ws + WK_OFF);
  float* kbias  = (float*)(ws + KB_OFF);
  int*   seg    = (int*)(ws + SEG_OFF);
  unsigned short* S_ws = (unsigned short*)(ws + S_OFF);
  unsigned short* attn = (unsigned short*)(ws + ATTN_OFF);

  k_q2 <<<2, 256, 0, stream>>>(qry, Wq, bq, q2);
  k_wk <<<17, 256, 0, stream>>>(Wk, bk, q2, wk_eff, kbias);
  k_seg<<<17, 256, 0, stream>>>(batch, N, seg);
  k_main<<<4096, 256, 0, stream>>>(emb, seg, wk_eff, kbias, S_ws);
  dim3 g(64, 8);
  k_gemm<true ><<<g, 256, 0, stream>>>(S_ws, (size_t)4096 * 512, Wv, bv, attn);
  k_gemm<false><<<g, 256, 0, stream>>>(attn, 0, Wo, bo, d_out);
}

// Round 2
// 364.835 us; speedup vs baseline: 1.0014x; 1.0014x over previous
//
#include <hip/hip_runtime.h>

#define LOG2E 1.4426950408889634f

// ---------------- ws layout (bytes) ----------------
#define WK_OFF   ((size_t)0)          // wk_eff f32 [8][512]
#define KB_OFF   ((size_t)16384)      // kbias f32 [8]
#define Q2_OFF   ((size_t)16416)      // q2 f32 [512]
#define SEG_OFF  ((size_t)18464)      // seg i32 [4097]
#define S_OFF    ((size_t)34880)      // S_ws bf16 [8][4096][512]
#define ATTN_OFF ((size_t)33589312)   // attn bf16 [4096][512]
#define WVHI_OFF ((size_t)37783616)   // Wv hi bf16 [512*512]
#define WVLO_OFF ((size_t)38307904)
#define WOHI_OFF ((size_t)38832192)
#define WOLO_OFF ((size_t)39356480)
#define WS_NEEDED ((size_t)39880768)

typedef __bf16 bf16x8 __attribute__((ext_vector_type(8)));
typedef float f32x4 __attribute__((ext_vector_type(4)));

__device__ __forceinline__ float readlane_f(float v, int l) {
  return __int_as_float(__builtin_amdgcn_readlane(__float_as_int(v), l));
}

__device__ __forceinline__ unsigned short f2bf(float x) {
  unsigned u = __float_as_uint(x);
  unsigned r = (u + 0x7fffu + ((u >> 16) & 1u)) >> 16;
  return (unsigned short)r;
}

__device__ __forceinline__ float bf2f(unsigned short h) {
  return __uint_as_float((unsigned)h << 16);
}

// ---------------- K0: fused prep (W hi/lo split + seg lower_bound + q2) ----------------
__global__ __launch_bounds__(256) void k_prep(
    const float* __restrict__ Wv, const float* __restrict__ Wo,
    unsigned short* __restrict__ wvhi, unsigned short* __restrict__ wvlo,
    unsigned short* __restrict__ wohi, unsigned short* __restrict__ wolo,
    const void* __restrict__ batch, int n, int* __restrict__ seg,
    const float* __restrict__ qry, const float* __restrict__ Wq,
    const float* __restrict__ bq, float* __restrict__ q2) {
  int bx = blockIdx.x;
  if (bx < 1024) {
    int i = bx * 256 + threadIdx.x;           // 0..262143
    float v = Wv[i];
    unsigned short h = f2bf(v);
    wvhi[i] = h;
    wvlo[i] = f2bf(v - bf2f(h));
    float o = Wo[i];
    unsigned short h2 = f2bf(o);
    wohi[i] = h2;
    wolo[i] = f2bf(o - bf2f(h2));
  } else if (bx < 1041) {
    int b = (bx - 1024) * 256 + threadIdx.x;  // 0..4096
    if (b > 4096) return;
    const int* b32 = (const int*)batch;
    const long long* b64 = (const long long*)batch;
    bool is64 = (b32[n - 1] == 0);            // int64 high word of last elem
    int lo = 0, hi = n;
    while (lo < hi) {
      int mid = (lo + hi) >> 1;
      long long v = is64 ? b64[mid] : (long long)b32[mid];
      if (v < (long long)b) lo = mid + 1; else hi = mid;
    }
    seg[b] = lo;
  } else {
    int d = (bx - 1041) * 256 + threadIdx.x;  // 0..511
    const float4* q4 = (const float4*)qry;
    const float4* w4 = (const float4*)(Wq + (size_t)d * 512);
    float acc = 0.f;
    #pragma unroll 4
    for (int j = 0; j < 128; ++j) {
      float4 a = q4[j], b = w4[j];
      acc += a.x * b.x + a.y * b.y + a.z * b.z + a.w * b.w;
    }
    q2[d] = (acc + bq[d]) * (0.125f * LOG2E);
  }
}

// ---------------- K1: wk_eff[h][e] = sum_d q2[h*64+d]*Wk[h*64+d][e]; kbias ----------------
__global__ __launch_bounds__(256) void k_wk(const float* __restrict__ Wk,
                                            const float* __restrict__ bk,
                                            const float* __restrict__ q2,
                                            float* __restrict__ wk,
                                            float* __restrict__ kb) {
  if (blockIdx.x == 16) {
    int h = threadIdx.x;
    if (h < 8) {
      float acc = 0.f;
      for (int dd = 0; dd < 64; ++dd) acc += q2[h * 64 + dd] * bk[h * 64 + dd];
      kb[h] = acc;
    }
    return;
  }
  int id = blockIdx.x * 256 + threadIdx.x;  // 0..4095
  int h = id >> 9, e = id & 511;
  float acc = 0.f;
  #pragma unroll 4
  for (int dd = 0; dd < 64; ++dd)
    acc += q2[h * 64 + dd] * Wk[(size_t)(h * 64 + dd) * 512 + e];
  wk[id] = acc;
}

// ---------------- K2: per-graph fused scores + softmax + weighted-emb pooling ----------------
// Each wave processes a PAIR of consecutive nodes per iteration (stride 8 across
// 4 waves) with pair-ahead prefetch: 4 KB/wave of loads in flight.
__global__ __launch_bounds__(256, 2) void k_main(const float* __restrict__ emb,
                                                 const int* __restrict__ seg,
                                                 const float* __restrict__ wk,
                                                 const float* __restrict__ kb,
                                                 unsigned short* __restrict__ S_ws) {
  __shared__ float sm[8232];
  const int tid = threadIdx.x;
  const int lane = tid & 63, wave = tid >> 6;
  const int b = blockIdx.x;
  const int s = seg[b], e2 = seg[b + 1];

  float4 wka[8], wkb[8];
  #pragma unroll
  for (int h = 0; h < 8; ++h) {
    wka[h] = *(const float4*)(wk + h * 512 + 4 * lane);
    wkb[h] = *(const float4*)(wk + h * 512 + 256 + 4 * lane);
  }
  const float kbl = kb[lane & 7];

  float4 Sa[8], Sb[8];
  #pragma unroll
  for (int h = 0; h < 8; ++h) {
    Sa[h] = make_float4(0.f, 0.f, 0.f, 0.f);
    Sb[h] = make_float4(0.f, 0.f, 0.f, 0.f);
  }
  float dn = 0.f;

  const float4* emb4 = (const float4*)emb;
  // transpose scratch: 16 scores/lane, row stride 17 (odd -> 2-way alias, free)
  const int pw = wave * 1088 + lane * 17;
  const int pr = wave * 1088 + (lane & 56) * 17 + (lane & 7);

  int i = s + wave * 2;
  if (i < e2) {
    size_t o = (size_t)i * 128 + lane;
    float4 a0 = emb4[o], a1 = emb4[o + 64];
    bool v1 = (i + 1) < e2;
    float4 a2, a3;
    if (v1) { a2 = emb4[o + 128]; a3 = emb4[o + 192]; }
    while (true) {
      int nx = i + 8;
      bool m0 = nx < e2;
      bool m1 = (nx + 1) < e2;
      float4 b0, b1, b2, b3;
      if (m0) {
        size_t o2 = (size_t)nx * 128 + lane;
        b0 = emb4[o2]; b1 = emb4[o2 + 64];
        if (m1) { b2 = emb4[o2 + 128]; b3 = emb4[o2 + 192]; }
      }
      // per-lane score partials for 8 heads, both nodes
      #pragma unroll
      for (int h = 0; h < 8; ++h) {
        float4 wa = wka[h], wb = wkb[h];
        sm[pw + h] = a0.x * wa.x + a0.y * wa.y + a0.z * wa.z + a0.w * wa.w +
                     a1.x * wb.x + a1.y * wb.y + a1.z * wb.z + a1.w * wb.w;
        if (v1)
          sm[pw + 8 + h] = a2.x * wa.x + a2.y * wa.y + a2.z * wa.z + a2.w * wa.w +
                           a3.x * wb.x + a3.y * wb.y + a3.z * wb.z + a3.w * wb.w;
      }
      // node 0: column sums + butterfly
      float hs0 = 0.f;
      #pragma unroll
      for (int j = 0; j < 8; ++j) hs0 += sm[pr + j * 17];
      hs0 += __shfl_xor(hs0, 8);
      hs0 += __shfl_xor(hs0, 16);
      hs0 += __shfl_xor(hs0, 32);
      float w0 = exp2f(hs0 + kbl);
      dn += w0;
      #pragma unroll
      for (int h = 0; h < 8; ++h) {
        float wh = readlane_f(w0, h);
        Sa[h].x += wh * a0.x; Sa[h].y += wh * a0.y; Sa[h].z += wh * a0.z; Sa[h].w += wh * a0.w;
        Sb[h].x += wh * a1.x; Sb[h].y += wh * a1.y; Sb[h].z += wh * a1.z; Sb[h].w += wh * a1.w;
      }
      if (v1) {
        float hs1 = 0.f;
        #pragma unroll
        for (int j = 0; j < 8; ++j) hs1 += sm[pr + 8 + j * 17];
        hs1 += __shfl_xor(hs1, 8);
        hs1 += __shfl_xor(hs1, 16);
        hs1 += __shfl_xor(hs1, 32);
        float w1 = exp2f(hs1 + kbl);
        dn += w1;
        #pragma unroll
        for (int h = 0; h < 8; ++h) {
          float wh = readlane_f(w1, h);
          Sa[h].x += wh * a2.x; Sa[h].y += wh * a2.y; Sa[h].z += wh * a2.z; Sa[h].w += wh * a2.w;
          Sb[h].x += wh * a3.x; Sb[h].y += wh * a3.y; Sb[h].z += wh * a3.z; Sb[h].w += wh * a3.w;
        }
      }
      if (!m0) break;
      i = nx;
      a0 = b0; a1 = b1;
      v1 = m1;
      if (m1) { a2 = b2; a3 = b3; }
    }
  }
  __syncthreads();

  // denominators
  if (lane < 8) sm[8192 + wave * 8 + lane] = dn;
  __syncthreads();
  if (tid < 8) {
    float d = sm[8192 + tid] + sm[8200 + tid] + sm[8208 + tid] + sm[8216 + tid];
    sm[8224 + tid] = (d > 0.f) ? 1.f / d : 0.f;
  }
  __syncthreads();

  // combine S across waves, halves A then B; write S' = S/denom as bf16
  #pragma unroll
  for (int h = 0; h < 8; ++h)
    *(float4*)&sm[wave * 2048 + h * 256 + 4 * lane] = Sa[h];
  __syncthreads();
  #pragma unroll
  for (int h = 0; h < 8; ++h) {
    float v = (sm[h * 256 + tid] + sm[2048 + h * 256 + tid] +
               sm[4096 + h * 256 + tid] + sm[6144 + h * 256 + tid]) * sm[8224 + h];
    S_ws[((size_t)h * 4096 + b) * 512 + tid] = f2bf(v);
  }
  __syncthreads();
  #pragma unroll
  for (int h = 0; h < 8; ++h)
    *(float4*)&sm[wave * 2048 + h * 256 + 4 * lane] = Sb[h];
  __syncthreads();
  #pragma unroll
  for (int h = 0; h < 8; ++h) {
    float v = (sm[h * 256 + tid] + sm[2048 + h * 256 + tid] +
               sm[4096 + h * 256 + tid] + sm[6144 + h * 256 + tid]) * sm[8224 + h];
    S_ws[((size_t)h * 4096 + b) * 512 + 256 + tid] = f2bf(v);
  }
}

// ---------------- K3/K4: MFMA NT GEMM, C[M=4096, 64-col strip per blockIdx.y] ----------------
// C = A(bf16, K=512 contiguous) . W^T + bias, W given as hi/lo bf16 split.
// Block: 64(M) x 64(N), 4 waves in 2x2, wave tile 32x32 (2x2 mfma frags).
template <bool C_BF16>
__global__ __launch_bounds__(256) void k_gemm_mfma(
    const unsigned short* __restrict__ A, size_t a_cb_stride,
    const unsigned short* __restrict__ Whi, const unsigned short* __restrict__ Wlo,
    const float* __restrict__ bias, void* __restrict__ Cv) {
  const int t = threadIdx.x;
  const int lane = t & 63, wvid = t >> 6;
  const int wr = wvid >> 1, wc = wvid & 1;
  const int row16 = lane & 15;
  const int k8 = (lane >> 4) * 8;
  const int mbase = blockIdx.x * 64 + wr * 32;
  const int nbase = blockIdx.y * 64 + wc * 32;

  const unsigned short* Ap = A + (size_t)blockIdx.y * a_cb_stride +
                             (size_t)(mbase + row16) * 512 + k8;
  const unsigned short* Wh = Whi + (size_t)(nbase + row16) * 512 + k8;
  const unsigned short* Wl = Wlo + (size_t)(nbase + row16) * 512 + k8;

  f32x4 acc[2][2] = {};

  #pragma unroll 4
  for (int kk = 0; kk < 512; kk += 32) {
    bf16x8 a0 = *(const bf16x8*)(Ap + kk);
    bf16x8 a1 = *(const bf16x8*)(Ap + 16 * 512 + kk);
    bf16x8 h0 = *(const bf16x8*)(Wh + kk);
    bf16x8 h1 = *(const bf16x8*)(Wh + 16 * 512 + kk);
    bf16x8 l0 = *(const bf16x8*)(Wl + kk);
    bf16x8 l1 = *(const bf16x8*)(Wl + 16 * 512 + kk);
    acc[0][0] = __builtin_amdgcn_mfma_f32_16x16x32_bf16(a0, h0, acc[0][0], 0, 0, 0);
    acc[0][1] = __builtin_amdgcn_mfma_f32_16x16x32_bf16(a0, h1, acc[0][1], 0, 0, 0);
    acc[1][0] = __builtin_amdgcn_mfma_f32_16x16x32_bf16(a1, h0, acc[1][0], 0, 0, 0);
    acc[1][1] = __builtin_amdgcn_mfma_f32_16x16x32_bf16(a1, h1, acc[1][1], 0, 0, 0);
    acc[0][0] = __builtin_amdgcn_mfma_f32_16x16x32_bf16(a0, l0, acc[0][0], 0, 0, 0);
    acc[0][1] = __builtin_amdgcn_mfma_f32_16x16x32_bf16(a0, l1, acc[0][1], 0, 0, 0);
    acc[1][0] = __builtin_amdgcn_mfma_f32_16x16x32_bf16(a1, l0, acc[1][0], 0, 0, 0);
    acc[1][1] = __builtin_amdgcn_mfma_f32_16x16x32_bf16(a1, l1, acc[1][1], 0, 0, 0);
  }

  const int r4 = (lane >> 4) * 4;
  #pragma unroll
  for (int c = 0; c < 2; ++c) {
    const float bc = bias[nbase + c * 16 + row16];
    #pragma unroll
    for (int r = 0; r < 2; ++r) {
      #pragma unroll
      for (int j = 0; j < 4; ++j) {
        float v = acc[r][c][j] + bc;
        size_t row = (size_t)(mbase + r * 16 + r4 + j);
        size_t col = (size_t)(nbase + c * 16 + row16);
        if (C_BF16)
          ((unsigned short*)Cv)[row * 512 + col] = f2bf(v);
        else
          ((float*)Cv)[row * 512 + col] = v;
      }
    }
  }
}

// ---------------- launcher ----------------
extern "C" void kernel_launch(void* const* d_in, const int* in_sizes, int n_in,
                              void* d_out, int out_size, void* d_ws, size_t ws_size,
                              hipStream_t stream) {
  const float* emb   = (const float*)d_in[0];
  const void*  batch = d_in[1];
  const float* qry   = (const float*)d_in[2];
  const float* Wq    = (const float*)d_in[3];
  const float* bq    = (const float*)d_in[4];
  const float* Wk    = (const float*)d_in[5];
  const float* bk    = (const float*)d_in[6];
  const float* Wv    = (const float*)d_in[7];
  const float* bv    = (const float*)d_in[8];
  const float* Wo    = (const float*)d_in[9];
  const float* bo    = (const float*)d_in[10];
  const int N = in_sizes[1];

  if (ws_size < WS_NEEDED) return;

  char* ws = (char*)d_ws;
  float* wk_eff = (float*)(ws + WK_OFF);
  float* kbias  = (float*)(ws + KB_OFF);
  float* q2     = (float*)(ws + Q2_OFF);
  int*   seg    = (int*)(ws + SEG_OFF);
  unsigned short* S_ws = (unsigned short*)(ws + S_OFF);
  unsigned short* attn = (unsigned short*)(ws + ATTN_OFF);
  unsigned short* wvhi = (unsigned short*)(ws + WVHI_OFF);
  unsigned short* wvlo = (unsigned short*)(ws + WVLO_OFF);
  unsigned short* wohi = (unsigned short*)(ws + WOHI_OFF);
  unsigned short* wolo = (unsigned short*)(ws + WOLO_OFF);

  k_prep<<<1043, 256, 0, stream>>>(Wv, Wo, wvhi, wvlo, wohi, wolo,
                                   batch, N, seg, qry, Wq, bq, q2);
  k_wk  <<<17, 256, 0, stream>>>(Wk, bk, q2, wk_eff, kbias);
  k_main<<<4096, 256, 0, stream>>>(emb, seg, wk_eff, kbias, S_ws);
  dim3 g(64, 8);
  k_gemm_mfma<true ><<<g, 256, 0, stream>>>(S_ws, (size_t)4096 * 512, wvhi, wvlo, bv, attn);
  k_gemm_mfma<false><<<g, 256, 0, stream>>>(attn, 0, wohi, wolo, bo, d_out);
}